// Round 4
// baseline (9425.114 us; speedup 1.0000x reference)
//
#include <hip/hip_runtime.h>
#include <math.h>

// ---------------- problem constants ----------------
#define B_    32
#define CIN   128
#define CHID  256
#define H_    60
#define W_    80
#define COUT  65
#define HP    480
#define WP    640
#define TOPK  1000
#define CAND_MAX 8192
#define DET_THRESH 0.015f

// ---------------- output layout (floats) ----------------
#define LOGITS_N (B_*COUT*H_*W_)        // 9,984,000
#define PROB_N   (B_*HP*WP)             // 9,830,400
#define PROB_OFF (LOGITS_N)
#define NMS_OFF  (PROB_OFF + PROB_N)
#define PRED_OFF (NMS_OFF + PROB_N)

// ---------------- workspace layout (float offsets) ----------------
#define WT_N   (CHID*CIN*9)             // 294,912
#define WT_OFF 0
#define SA_OFF (WT_OFF + WT_N)
#define TA_OFF (SA_OFF + 256)
#define TB_OFF (TA_OFF + 256)
#define WT1_N  (COUT*CHID)              // 16,640
#define WT1_OFF (TB_OFF + 128)
#define H_OFF  (WT1_OFF + WT1_N)
#define H_N    (B_*H_*W_*CHID)          // 39,321,600
#define CAND_OFF (H_OFF + H_N)
#define CNT_OFF  (CAND_OFF + B_*CAND_MAX)
#define CNT_N    (32*32)
#define KTH_OFF  (CNT_OFF + CNT_N)

// async global->LDS, 16B per lane (lds dest = uniform base + lane*16)
__device__ __forceinline__ void gload_lds16(const float* g, float* l) {
    __builtin_amdgcn_global_load_lds(
        (const __attribute__((address_space(1))) void*)g,
        (__attribute__((address_space(3))) void*)l, 16, 0, 0);
}

// =====================================================================
// K0: prep — wt2: [cc16][ot4][ic8][tap9][oc64] contiguous slices for
// gload_lds; sa/ta conv3 BN; wt1 = wb*scale (conv1 folded), tb bias.
// =====================================================================
__global__ void prep_kernel(const float* __restrict__ wa,
                            const float* __restrict__ ba, const float* __restrict__ ga,
                            const float* __restrict__ bta, const float* __restrict__ ma,
                            const float* __restrict__ va,
                            const float* __restrict__ wb, const float* __restrict__ bb,
                            const float* __restrict__ gb, const float* __restrict__ btb,
                            const float* __restrict__ mb, const float* __restrict__ vb,
                            float* __restrict__ wt2,
                            float* __restrict__ sa, float* __restrict__ ta,
                            float* __restrict__ tb, float* __restrict__ wt1)
{
    int gid = blockIdx.x * 256 + threadIdx.x;
    if (gid < WT_N) {
        int i = gid;
        int ocl = i & 63;
        int tap = (i >> 6) % 9;
        int icl = (i / 576) & 7;
        int ot  = (i / 4608) & 3;
        int cc  = i / 18432;
        int oc = ot * 64 + ocl;
        int ic = cc * 8 + icl;
        wt2[gid] = wa[(oc * CIN + ic) * 9 + tap];
    } else if (gid < WT_N + 256) {
        int oc = gid - WT_N;
        float inv = ga[oc] / sqrtf(va[oc] + 1e-5f);
        sa[oc] = inv;
        ta[oc] = (ba[oc] - ma[oc]) * inv + bta[oc];
    } else if (gid < WT_N + 256 + COUT) {
        int oc = gid - (WT_N + 256);
        float inv = gb[oc] / sqrtf(vb[oc] + 1e-5f);
        tb[oc] = (bb[oc] - mb[oc]) * inv + btb[oc];
    } else if (gid < WT_N + 256 + COUT + WT1_N) {
        int i = gid - (WT_N + 256 + COUT);
        int oc = i >> 8;
        float inv = gb[oc] / sqrtf(vb[oc] + 1e-5f);
        wt1[i] = wb[i] * inv;
    }
}

// =====================================================================
// K1: conv3x3 (128->256) + BN + ReLU, double-buffered pipeline:
//   w via global_load_lds (contiguous slices), x via reg-prefetch + late ds_write
// =====================================================================
__global__ __launch_bounds__(256) void conv3_kernel(const float* __restrict__ x,
                                                    const float* __restrict__ wt2,
                                                    const float* __restrict__ sa,
                                                    const float* __restrict__ ta,
                                                    float* __restrict__ h)
{
    __shared__ __align__(16) float xs[2][8][18][20];   // 23040 B
    __shared__ __align__(16) float wsh[2][4608];       // 36864 B

    int bid = blockIdx.x;
    int ct = bid % 5;
    int rt = (bid / 5) & 3;
    int ot = (bid / 20) & 3;
    int b  = bid / 80;
    int x0 = ct * 16, y0 = rt * 16, oc0 = ot * 64;

    int t = threadIdx.x;
    int wave = t >> 6, lane = t & 63;
    int toc = t & 7;
    int g = t >> 3;
    int trow = g & 15;
    int c0 = (g >> 4) * 8;

    const float* xb = x + (size_t)b * CIN * H_ * W_;

    float acc[8][8];
#pragma unroll
    for (int o = 0; o < 8; ++o)
#pragma unroll
        for (int p = 0; p < 8; ++p) acc[o][p] = 0.f;

    float xr[11];

    // ---- prologue: stage cc=0 into buf 0 ----
    {
        const float* wsrc = wt2 + (size_t)(0 * 4 + ot) * 4608;
        for (int k = wave; k < 18; k += 4)
            gload_lds16(wsrc + k * 256 + lane * 4, &wsh[0][k * 256]);
        const float* xsrc = xb;   // ic0 = 0
#pragma unroll
        for (int j = 0; j < 11; ++j) {
            int idx = t + j * 256;
            float v = 0.f;
            if (idx < 2592) {
                int c = idx % 18, rr = (idx / 18) % 18, icl = idx / 324;
                int gy = y0 - 1 + rr, gx = x0 - 1 + c;
                if (gy >= 0 && gy < H_ && gx >= 0 && gx < W_)
                    v = xsrc[icl * (H_ * W_) + gy * W_ + gx];
            }
            xr[j] = v;
        }
#pragma unroll
        for (int j = 0; j < 11; ++j) {
            int idx = t + j * 256;
            if (idx < 2592) {
                int c = idx % 18, rr = (idx / 18) % 18, icl = idx / 324;
                xs[0][icl][rr][c] = xr[j];
            }
        }
    }

#pragma unroll 1
    for (int cc = 0; cc < 16; ++cc) {
        int buf = cc & 1, nbuf = buf ^ 1;
        __syncthreads();   // drains vmcnt (gload_lds) + lgkm; buf ready for all

        // issue next-tile staging (hidden under compute)
        if (cc < 15) {
            const float* wsrc = wt2 + (size_t)((cc + 1) * 4 + ot) * 4608;
            for (int k = wave; k < 18; k += 4)
                gload_lds16(wsrc + k * 256 + lane * 4, &wsh[nbuf][k * 256]);
            const float* xsrc = xb + (cc + 1) * 8 * (H_ * W_);
#pragma unroll
            for (int j = 0; j < 11; ++j) {
                int idx = t + j * 256;
                float v = 0.f;
                if (idx < 2592) {
                    int c = idx % 18, rr = (idx / 18) % 18, icl = idx / 324;
                    int gy = y0 - 1 + rr, gx = x0 - 1 + c;
                    if (gy >= 0 && gy < H_ && gx >= 0 && gx < W_)
                        v = xsrc[icl * (H_ * W_) + gy * W_ + gx];
                }
                xr[j] = v;
            }
        }

        // ---- compute current buffer ----
        {
            const float* wbase = wsh[buf];
#pragma unroll
            for (int ic = 0; ic < 8; ++ic) {
#pragma unroll
                for (int dy = 0; dy < 3; ++dy) {
                    float4 xa = *(const float4*)&xs[buf][ic][trow + dy][c0];
                    float4 xbv = *(const float4*)&xs[buf][ic][trow + dy][c0 + 4];
                    float4 xc = *(const float4*)&xs[buf][ic][trow + dy][c0 + 8];
                    float xv[12] = {xa.x, xa.y, xa.z, xa.w,
                                    xbv.x, xbv.y, xbv.z, xbv.w,
                                    xc.x, xc.y, xc.z, xc.w};
#pragma unroll
                    for (int dx = 0; dx < 3; ++dx) {
                        const float* wrow = wbase + ic * 576 + (dy * 3 + dx) * 64 + toc * 8;
                        float4 w0 = *(const float4*)wrow;
                        float4 w1 = *(const float4*)(wrow + 4);
                        float wv[8] = {w0.x, w0.y, w0.z, w0.w, w1.x, w1.y, w1.z, w1.w};
#pragma unroll
                        for (int p = 0; p < 8; ++p)
#pragma unroll
                            for (int o = 0; o < 8; ++o)
                                acc[o][p] = fmaf(wv[o], xv[p + dx], acc[o][p]);
                    }
                }
            }
        }

        // late ds_write of prefetched x (waits only on x loads; w gloads stay in flight)
        if (cc < 15) {
#pragma unroll
            for (int j = 0; j < 11; ++j) {
                int idx = t + j * 256;
                if (idx < 2592) {
                    int c = idx % 18, rr = (idx / 18) % 18, icl = idx / 324;
                    xs[nbuf][icl][rr][c] = xr[j];
                }
            }
        }
    }

    // ---- epilogue: BN + ReLU, store channel-last ----
    int y = y0 + trow;
    if (y < H_) {
        float s[8], tt[8];
#pragma unroll
        for (int o = 0; o < 8; ++o) {
            s[o] = sa[oc0 + toc * 8 + o];
            tt[o] = ta[oc0 + toc * 8 + o];
        }
        int px_base = b * (H_ * W_) + y * W_ + x0 + c0;
#pragma unroll
        for (int p = 0; p < 8; ++p) {
            float4 v0, v1;
            v0.x = fmaxf(fmaf(acc[0][p], s[0], tt[0]), 0.f);
            v0.y = fmaxf(fmaf(acc[1][p], s[1], tt[1]), 0.f);
            v0.z = fmaxf(fmaf(acc[2][p], s[2], tt[2]), 0.f);
            v0.w = fmaxf(fmaf(acc[3][p], s[3], tt[3]), 0.f);
            v1.x = fmaxf(fmaf(acc[4][p], s[4], tt[4]), 0.f);
            v1.y = fmaxf(fmaf(acc[5][p], s[5], tt[5]), 0.f);
            v1.z = fmaxf(fmaf(acc[6][p], s[6], tt[6]), 0.f);
            v1.w = fmaxf(fmaf(acc[7][p], s[7], tt[7]), 0.f);
            float* hp = h + (size_t)(px_base + p) * CHID + oc0 + toc * 8;
            *(float4*)hp = v0;
            *(float4*)(hp + 4) = v1;
        }
    }
}

// =====================================================================
// K2: conv1x1 (256->65) + BN: weights (64 oc) staged in 64KB LDS via
// global_load_lds; broadcast ds_reads; oc=64 via uniform global loads.
// =====================================================================
__global__ __launch_bounds__(256) void conv1_kernel(const float* __restrict__ h,
                                                    const float* __restrict__ wt1,
                                                    const float* __restrict__ tb,
                                                    float* __restrict__ logits,
                                                    float* __restrict__ prob)
{
    __shared__ __align__(16) float ws_[64 * 256];    // 65536 B
    int t = threadIdx.x;
    int wave = t >> 6, lane = t & 63;

    for (int k = wave; k < 64; k += 4)
        gload_lds16(wt1 + k * 256 + lane * 4, &ws_[k * 256]);

    int p = blockIdx.x * 256 + t;
    const float* hp = h + (size_t)p * CHID;
    const float* w64g = wt1 + 64 * 256;

    float acc[COUT];
#pragma unroll
    for (int oc = 0; oc < COUT; ++oc) acc[oc] = 0.f;

    __syncthreads();   // drains gload_lds

#pragma unroll 2
    for (int kc = 0; kc < 32; ++kc) {
        float4 h0 = *(const float4*)(hp + kc * 8);
        float4 h1 = *(const float4*)(hp + kc * 8 + 4);
        float hv[8] = {h0.x, h0.y, h0.z, h0.w, h1.x, h1.y, h1.z, h1.w};

        // oc = 64: uniform global weights
        {
            float4 w0 = *(const float4*)(w64g + kc * 8);
            float4 w1 = *(const float4*)(w64g + kc * 8 + 4);
            float a = acc[64];
            a = fmaf(w0.x, hv[0], a); a = fmaf(w0.y, hv[1], a);
            a = fmaf(w0.z, hv[2], a); a = fmaf(w0.w, hv[3], a);
            a = fmaf(w1.x, hv[4], a); a = fmaf(w1.y, hv[5], a);
            a = fmaf(w1.z, hv[6], a); a = fmaf(w1.w, hv[7], a);
            acc[64] = a;
        }
#pragma unroll
        for (int oc = 0; oc < 64; ++oc) {
            const float* wr = ws_ + oc * 256 + kc * 8;
            float4 w0 = *(const float4*)wr;
            float4 w1 = *(const float4*)(wr + 4);
            float a = acc[oc];
            a = fmaf(w0.x, hv[0], a); a = fmaf(w0.y, hv[1], a);
            a = fmaf(w0.z, hv[2], a); a = fmaf(w0.w, hv[3], a);
            a = fmaf(w1.x, hv[4], a); a = fmaf(w1.y, hv[5], a);
            a = fmaf(w1.z, hv[6], a); a = fmaf(w1.w, hv[7], a);
            acc[oc] = a;
        }
    }

    int b = p / (H_ * W_);
    int yx = p % (H_ * W_);
    int y = yx / W_;
    int xx = yx % W_;

    float v[COUT];
#pragma unroll
    for (int oc = 0; oc < COUT; ++oc)
        v[oc] = acc[oc] + tb[oc];

#pragma unroll
    for (int oc = 0; oc < COUT; ++oc)
        logits[((size_t)(b * COUT + oc)) * (H_ * W_) + yx] = v[oc];

    float* pb = prob + (size_t)b * (HP * WP);
#pragma unroll
    for (int r1 = 0; r1 < 8; ++r1) {
        float4 a0, a1;
        a0.x = v[r1 * 8 + 0]; a0.y = v[r1 * 8 + 1]; a0.z = v[r1 * 8 + 2]; a0.w = v[r1 * 8 + 3];
        a1.x = v[r1 * 8 + 4]; a1.y = v[r1 * 8 + 5]; a1.z = v[r1 * 8 + 6]; a1.w = v[r1 * 8 + 7];
        float* dst = pb + (y * 8 + r1) * WP + xx * 8;
        *(float4*)dst = a0;
        *(float4*)(dst + 4) = a1;
    }
}

// =====================================================================
// K3: 9x9 local-max keep + candidate compaction (LDS compaction, 1 atomic/block)
// =====================================================================
__global__ __launch_bounds__(256) void nms_kernel(const float* __restrict__ prob,
                                                  float* __restrict__ keep_out,
                                                  float* __restrict__ cand,
                                                  int* __restrict__ cnt)
{
    __shared__ float xs[40][40];
    __shared__ float rmax[40][32];
    __shared__ float clist[1024];
    __shared__ int csh;
    __shared__ int gbase;

    int bid = blockIdx.x;
    int tx = bid % 20;
    int ty = (bid / 20) % 15;
    int b = bid / 300;
    const float* pb = prob + (size_t)b * (HP * WP);
    int t = threadIdx.x;

    if (t == 0) csh = 0;

    for (int idx = t; idx < 1600; idx += 256) {
        int c = idx % 40, r = idx / 40;
        int gy = ty * 32 - 4 + r;
        int gx = tx * 32 - 4 + c;
        float v = -INFINITY;
        if (gy >= 0 && gy < HP && gx >= 0 && gx < WP) v = pb[gy * WP + gx];
        xs[r][c] = v;
    }
    __syncthreads();

    for (int idx = t; idx < 1280; idx += 256) {
        int c = idx & 31, r = idx >> 5;
        float m = xs[r][c];
#pragma unroll
        for (int d = 1; d < 9; ++d) m = fmaxf(m, xs[r][c + d]);
        rmax[r][c] = m;
    }
    __syncthreads();

    for (int idx = t; idx < 1024; idx += 256) {
        int c = idx & 31, ro = idx >> 5;
        float m = rmax[ro][c];
#pragma unroll
        for (int d = 1; d < 9; ++d) m = fmaxf(m, rmax[ro + d][c]);
        float v = xs[ro + 4][c + 4];
        float keep = (v == m) ? v : 0.f;
        keep_out[(size_t)b * (HP * WP) + (ty * 32 + ro) * WP + tx * 32 + c] = keep;
        if (keep > 0.f) {
            int i = atomicAdd(&csh, 1);
            clist[i] = keep;
        }
    }
    __syncthreads();

    int m = csh;
    if (m > 0) {
        if (t == 0) gbase = atomicAdd(&cnt[b * 32], m);
        __syncthreads();
        int gb = gbase;
        for (int i = t; i < m; i += 256) {
            int dst = gb + i;
            if (dst < CAND_MAX) cand[b * CAND_MAX + dst] = clist[i];
        }
    }
}

// =====================================================================
// K4: exact kth-largest (k=1000) per batch via 4-pass radix select
// =====================================================================
__global__ __launch_bounds__(256) void select_kernel(const float* __restrict__ cand,
                                                     const int* __restrict__ cnt,
                                                     float* __restrict__ kth)
{
    __shared__ unsigned hist[256];
    __shared__ unsigned sh_prefix, sh_K;

    int b = blockIdx.x;
    int t = threadIdx.x;
    int n = cnt[b * 32];
    if (n > CAND_MAX) n = CAND_MAX;
    if (n < TOPK) {
        if (t == 0) kth[b] = 0.f;
        return;
    }
    if (t == 0) { sh_prefix = 0u; sh_K = TOPK; }
    __syncthreads();
    const float* cb = cand + b * CAND_MAX;

    for (int pass = 3; pass >= 0; --pass) {
        hist[t] = 0u;
        __syncthreads();
        unsigned prefix = sh_prefix;
        unsigned himask = (pass == 3) ? 0u : (0xFFFFFFFFu << ((pass + 1) * 8));
        for (int i = t; i < n; i += 256) {
            unsigned u = __float_as_uint(cb[i]);
            if ((u & himask) == prefix)
                atomicAdd(&hist[(u >> (pass * 8)) & 255], 1u);
        }
        __syncthreads();
        if (t == 0) {
            unsigned K = sh_K, cum = 0;
            int sel = 0;
            for (int v2 = 255; v2 >= 0; --v2) {
                if (cum + hist[v2] >= K) { sel = v2; sh_K = K - cum; break; }
                cum += hist[v2];
            }
            sh_prefix = prefix | ((unsigned)sel << (pass * 8));
        }
        __syncthreads();
    }
    if (t == 0) kth[b] = __uint_as_float(sh_prefix);
}

// =====================================================================
// K5: threshold with kth + binarize
// =====================================================================
__global__ __launch_bounds__(256) void thresh_kernel(const float* __restrict__ keep,
                                                     const float* __restrict__ kth,
                                                     float* __restrict__ prob_nms,
                                                     float* __restrict__ pred)
{
    int i4 = blockIdx.x * 256 + threadIdx.x;
    int b = i4 / (HP * WP / 4);
    float tv = kth[b];
    float4 v = ((const float4*)keep)[i4];
    float4 o;
    o.x = (v.x >= tv) ? v.x : 0.f;
    o.y = (v.y >= tv) ? v.y : 0.f;
    o.z = (v.z >= tv) ? v.z : 0.f;
    o.w = (v.w >= tv) ? v.w : 0.f;
    ((float4*)prob_nms)[i4] = o;
    float4 pr;
    pr.x = (o.x >= DET_THRESH) ? 1.f : 0.f;
    pr.y = (o.y >= DET_THRESH) ? 1.f : 0.f;
    pr.z = (o.z >= DET_THRESH) ? 1.f : 0.f;
    pr.w = (o.w >= DET_THRESH) ? 1.f : 0.f;
    ((float4*)pred)[i4] = pr;
}

// =====================================================================
extern "C" void kernel_launch(void* const* d_in, const int* in_sizes, int n_in,
                              void* d_out, int out_size, void* d_ws, size_t ws_size,
                              hipStream_t stream) {
    const float* x   = (const float*)d_in[0];
    const float* wa  = (const float*)d_in[1];
    const float* ba  = (const float*)d_in[2];
    const float* ga  = (const float*)d_in[3];
    const float* bta = (const float*)d_in[4];
    const float* ma  = (const float*)d_in[5];
    const float* va  = (const float*)d_in[6];
    const float* wb  = (const float*)d_in[7];
    const float* bb  = (const float*)d_in[8];
    const float* gb  = (const float*)d_in[9];
    const float* btb = (const float*)d_in[10];
    const float* mb  = (const float*)d_in[11];
    const float* vb  = (const float*)d_in[12];

    float* out = (float*)d_out;
    float* ws  = (float*)d_ws;

    float* wt2  = ws + WT_OFF;
    float* sa   = ws + SA_OFF;
    float* ta   = ws + TA_OFF;
    float* tbv  = ws + TB_OFF;
    float* wt1  = ws + WT1_OFF;
    float* h    = ws + H_OFF;
    float* cand = ws + CAND_OFF;
    int*   cnt  = (int*)(ws + CNT_OFF);
    float* kth  = ws + KTH_OFF;

    hipMemsetAsync((void*)cnt, 0, CNT_N * sizeof(int), stream);

    {
        int total = WT_N + 256 + COUT + WT1_N;
        prep_kernel<<<(total + 255) / 256, 256, 0, stream>>>(
            wa, ba, ga, bta, ma, va, wb, bb, gb, btb, mb, vb, wt2, sa, ta, tbv, wt1);
    }

    conv3_kernel<<<B_ * 80, 256, 0, stream>>>(x, wt2, sa, ta, h);

    conv1_kernel<<<(B_ * H_ * W_) / 256, 256, 0, stream>>>(
        h, wt1, tbv, out, out + PROB_OFF);

    nms_kernel<<<32 * 15 * 20, 256, 0, stream>>>(
        out + PROB_OFF, out + NMS_OFF, cand, cnt);

    select_kernel<<<B_, 256, 0, stream>>>(cand, cnt, kth);

    thresh_kernel<<<(PROB_N / 4) / 256, 256, 0, stream>>>(
        out + NMS_OFF, kth, out + NMS_OFF, out + PRED_OFF);
}

// Round 5
// 1783.065 us; speedup vs baseline: 5.2859x; 5.2859x over previous
//
#include <hip/hip_runtime.h>
#include <math.h>

// ---------------- problem constants ----------------
#define B_    32
#define CIN   128
#define CHID  256
#define H_    60
#define W_    80
#define COUT  65
#define HP    480
#define WP    640
#define TOPK  1000
#define CAND_MAX 8192
#define DET_THRESH 0.015f

// ---------------- output layout (floats) ----------------
#define LOGITS_N (B_*COUT*H_*W_)        // 9,984,000
#define PROB_N   (B_*HP*WP)             // 9,830,400
#define PROB_OFF (LOGITS_N)
#define NMS_OFF  (PROB_OFF + PROB_N)
#define PRED_OFF (NMS_OFF + PROB_N)

// ---------------- workspace layout (float offsets) ----------------
#define WT_N   (CHID*CIN*9)             // 294,912
#define WT_OFF 0
#define SA_OFF (WT_OFF + WT_N)
#define TA_OFF (SA_OFF + 256)
#define TB_OFF (TA_OFF + 256)
#define WT1_N  (COUT*CHID)              // 16,640
#define WT1_OFF (TB_OFF + 128)
#define H_OFF  (WT1_OFF + WT1_N)
#define H_N    (B_*H_*W_*CHID)          // 39,321,600
#define CAND_OFF (H_OFF + H_N)
#define CNT_OFF  (CAND_OFF + B_*CAND_MAX)
#define CNT_N    (32*32)
#define KTH_OFF  (CNT_OFF + CNT_N)

// async global->LDS, 16B per lane (lds dest = uniform base + lane*16)
__device__ __forceinline__ void gload_lds16(const float* g, float* l) {
    __builtin_amdgcn_global_load_lds(
        (const __attribute__((address_space(1))) void*)g,
        (__attribute__((address_space(3))) void*)l, 16, 0, 0);
}

// =====================================================================
// K0: prep.
//  wt3: conv3 weights laid out [cc16][icl8][tap9][wq16][k16] so a wave's
//       16-oc slice for one (ic,tap) is 16 contiguous 64B-aligned floats
//       (oc = wq*16 + k).  sa/ta: conv3 BN.  wt1 = wb*scale, tb: conv1 BN.
// =====================================================================
__global__ void prep_kernel(const float* __restrict__ wa,
                            const float* __restrict__ ba, const float* __restrict__ ga,
                            const float* __restrict__ bta, const float* __restrict__ ma,
                            const float* __restrict__ va,
                            const float* __restrict__ wb, const float* __restrict__ bb,
                            const float* __restrict__ gb, const float* __restrict__ btb,
                            const float* __restrict__ mb, const float* __restrict__ vb,
                            float* __restrict__ wt3,
                            float* __restrict__ sa, float* __restrict__ ta,
                            float* __restrict__ tb, float* __restrict__ wt1)
{
    int gid = blockIdx.x * 256 + threadIdx.x;
    if (gid < WT_N) {
        int k   = gid & 15;
        int wq  = (gid >> 4) & 15;
        int rest = gid >> 8;           // [0, 1152)
        int tap = rest % 9;
        int icr = rest / 9;            // [0, 128)
        int icl = icr & 7;
        int cc  = icr >> 3;
        int oc = wq * 16 + k;
        int ic = cc * 8 + icl;
        wt3[gid] = wa[(oc * CIN + ic) * 9 + tap];
    } else if (gid < WT_N + 256) {
        int oc = gid - WT_N;
        float inv = ga[oc] / sqrtf(va[oc] + 1e-5f);
        sa[oc] = inv;
        ta[oc] = (ba[oc] - ma[oc]) * inv + bta[oc];
    } else if (gid < WT_N + 256 + COUT) {
        int oc = gid - (WT_N + 256);
        float inv = gb[oc] / sqrtf(vb[oc] + 1e-5f);
        tb[oc] = (bb[oc] - mb[oc]) * inv + btb[oc];
    } else if (gid < WT_N + 256 + COUT + WT1_N) {
        int i = gid - (WT_N + 256 + COUT);
        int oc = i >> 8;
        float inv = gb[oc] / sqrtf(vb[oc] + 1e-5f);
        wt1[i] = wb[i] * inv;
    }
}

// =====================================================================
// K1: conv3x3 (128->256) + BN + ReLU.
// Block = 16x16 px tile x 64-oc slice. Wave = 16 oc x all 256 px.
// Lane = 16 oc x 4 px.  Weights: wave-uniform s_load (SGPR), never LDS.
// LDS: x tile only, 8ic x 18 x 20 (11.5 KB), single-buffered.
// =====================================================================
__global__ __launch_bounds__(256) void conv3_kernel(const float* __restrict__ x,
                                                    const float* __restrict__ wt3,
                                                    const float* __restrict__ sa,
                                                    const float* __restrict__ ta,
                                                    float* __restrict__ h)
{
    __shared__ __align__(16) float xs[8 * 18 * 20];   // 11520 B

    // bijective XCD swizzle (2560 blocks / 8 XCDs = 320 each), ot fastest:
    // the 4 oc-slice siblings of one spatial tile stay on one XCD's L2.
    int d = blockIdx.x;
    int o = (d & 7) * 320 + (d >> 3);
    int ot = o & 3;
    int tile = (o >> 2) % 20;       // rt*5+ct
    int b = o / 80;
    int ct = tile % 5, rt = tile / 5;
    int x0 = ct * 16, y0 = rt * 16;

    int t = threadIdx.x;
    int wv = __builtin_amdgcn_readfirstlane(t >> 6);   // 0..3, uniform
    int lane = t & 63;
    int row = lane >> 2;            // 0..15
    int cg  = lane & 3;             // cols cg*4 .. cg*4+3
    int wq = ot * 4 + wv;           // 16-oc slice id, uniform

    const float* xb = x + (size_t)b * CIN * H_ * W_;

    // precompute staging offsets (12 per thread, reused all 16 K-steps)
    int goff[12];
#pragma unroll
    for (int j = 0; j < 12; ++j) {
        int idx = t + j * 256;
        int go = -1;
        if (idx < 2880) {
            int c = idx % 20;
            int rr = (idx / 20) % 18;
            int icl = idx / 360;
            int gy = y0 - 1 + rr;
            int gx = x0 - 1 + c;
            if (c < 18 && gy >= 0 && gy < H_ && gx >= 0 && gx < W_)
                go = icl * (H_ * W_) + gy * W_ + gx;
        }
        goff[j] = go;
    }

    float acc[16][4];
#pragma unroll
    for (int o2 = 0; o2 < 16; ++o2)
#pragma unroll
        for (int p = 0; p < 4; ++p) acc[o2][p] = 0.f;

#pragma unroll 1
    for (int cc = 0; cc < 16; ++cc) {
        __syncthreads();
        // stage x tile (linear LDS, pads/OOB get 0)
        const float* xc = xb + cc * 8 * (H_ * W_);
#pragma unroll
        for (int j = 0; j < 12; ++j) {
            int idx = t + j * 256;
            if (idx < 2880) {
                int go = goff[j];
                float v = (go >= 0) ? xc[go] : 0.f;
                xs[idx] = v;
            }
        }
        __syncthreads();

        // weights for this K-step: uniform base -> s_load_dwordx16 per (ic,tap)
        const float* wp = wt3 + (size_t)cc * 18432 + wq * 16;

#pragma unroll
        for (int icl = 0; icl < 8; ++icl) {
            const float* xi = xs + icl * 360;
            const float* wi = wp + icl * 2304;
#pragma unroll
            for (int dy = 0; dy < 3; ++dy) {
                float4 xa = *(const float4*)&xi[(row + dy) * 20 + cg * 4];
                float2 xb2 = *(const float2*)&xi[(row + dy) * 20 + cg * 4 + 4];
                float xv[6] = {xa.x, xa.y, xa.z, xa.w, xb2.x, xb2.y};
#pragma unroll
                for (int dx = 0; dx < 3; ++dx) {
                    const float* wr = wi + (dy * 3 + dx) * 256;
                    float w16[16];
#pragma unroll
                    for (int k = 0; k < 16; ++k) w16[k] = wr[k];
#pragma unroll
                    for (int o2 = 0; o2 < 16; ++o2)
#pragma unroll
                        for (int p = 0; p < 4; ++p)
                            acc[o2][p] = fmaf(w16[o2], xv[p + dx], acc[o2][p]);
                }
            }
        }
    }

    // epilogue: BN + ReLU, channel-last store
    int y = y0 + row;
    if (y < H_) {
        int oc0 = wq * 16;
        float s_[16], t_[16];
#pragma unroll
        for (int o2 = 0; o2 < 16; ++o2) {
            s_[o2] = sa[oc0 + o2];
            t_[o2] = ta[oc0 + o2];
        }
        int px_base = b * (H_ * W_) + y * W_ + x0 + cg * 4;
#pragma unroll
        for (int p = 0; p < 4; ++p) {
            float* hp = h + (size_t)(px_base + p) * CHID + oc0;
#pragma unroll
            for (int og = 0; og < 4; ++og) {
                float4 v;
                v.x = fmaxf(fmaf(acc[og * 4 + 0][p], s_[og * 4 + 0], t_[og * 4 + 0]), 0.f);
                v.y = fmaxf(fmaf(acc[og * 4 + 1][p], s_[og * 4 + 1], t_[og * 4 + 1]), 0.f);
                v.z = fmaxf(fmaf(acc[og * 4 + 2][p], s_[og * 4 + 2], t_[og * 4 + 2]), 0.f);
                v.w = fmaxf(fmaf(acc[og * 4 + 3][p], s_[og * 4 + 3], t_[og * 4 + 3]), 0.f);
                *(float4*)(hp + og * 4) = v;
            }
        }
    }
}

// =====================================================================
// K2: conv1x1 (256->65) + BN: weights (64 oc) staged in 64KB LDS via
// global_load_lds; broadcast ds_reads; oc=64 via uniform global loads.
// =====================================================================
__global__ __launch_bounds__(256) void conv1_kernel(const float* __restrict__ h,
                                                    const float* __restrict__ wt1,
                                                    const float* __restrict__ tb,
                                                    float* __restrict__ logits,
                                                    float* __restrict__ prob)
{
    __shared__ __align__(16) float ws_[64 * 256];    // 65536 B
    int t = threadIdx.x;
    int wave = t >> 6, lane = t & 63;

    for (int k = wave; k < 64; k += 4)
        gload_lds16(wt1 + k * 256 + lane * 4, &ws_[k * 256]);

    int p = blockIdx.x * 256 + t;
    const float* hp = h + (size_t)p * CHID;
    const float* w64g = wt1 + 64 * 256;

    float acc[COUT];
#pragma unroll
    for (int oc = 0; oc < COUT; ++oc) acc[oc] = 0.f;

    __syncthreads();   // drains gload_lds

#pragma unroll 2
    for (int kc = 0; kc < 32; ++kc) {
        float4 h0 = *(const float4*)(hp + kc * 8);
        float4 h1 = *(const float4*)(hp + kc * 8 + 4);
        float hv[8] = {h0.x, h0.y, h0.z, h0.w, h1.x, h1.y, h1.z, h1.w};

        {
            float4 w0 = *(const float4*)(w64g + kc * 8);
            float4 w1 = *(const float4*)(w64g + kc * 8 + 4);
            float a = acc[64];
            a = fmaf(w0.x, hv[0], a); a = fmaf(w0.y, hv[1], a);
            a = fmaf(w0.z, hv[2], a); a = fmaf(w0.w, hv[3], a);
            a = fmaf(w1.x, hv[4], a); a = fmaf(w1.y, hv[5], a);
            a = fmaf(w1.z, hv[6], a); a = fmaf(w1.w, hv[7], a);
            acc[64] = a;
        }
#pragma unroll
        for (int oc = 0; oc < 64; ++oc) {
            const float* wr = ws_ + oc * 256 + kc * 8;
            float4 w0 = *(const float4*)wr;
            float4 w1 = *(const float4*)(wr + 4);
            float a = acc[oc];
            a = fmaf(w0.x, hv[0], a); a = fmaf(w0.y, hv[1], a);
            a = fmaf(w0.z, hv[2], a); a = fmaf(w0.w, hv[3], a);
            a = fmaf(w1.x, hv[4], a); a = fmaf(w1.y, hv[5], a);
            a = fmaf(w1.z, hv[6], a); a = fmaf(w1.w, hv[7], a);
            acc[oc] = a;
        }
    }

    int b = p / (H_ * W_);
    int yx = p % (H_ * W_);
    int y = yx / W_;
    int xx = yx % W_;

    float v[COUT];
#pragma unroll
    for (int oc = 0; oc < COUT; ++oc)
        v[oc] = acc[oc] + tb[oc];

#pragma unroll
    for (int oc = 0; oc < COUT; ++oc)
        logits[((size_t)(b * COUT + oc)) * (H_ * W_) + yx] = v[oc];

    float* pb = prob + (size_t)b * (HP * WP);
#pragma unroll
    for (int r1 = 0; r1 < 8; ++r1) {
        float4 a0, a1;
        a0.x = v[r1 * 8 + 0]; a0.y = v[r1 * 8 + 1]; a0.z = v[r1 * 8 + 2]; a0.w = v[r1 * 8 + 3];
        a1.x = v[r1 * 8 + 4]; a1.y = v[r1 * 8 + 5]; a1.z = v[r1 * 8 + 6]; a1.w = v[r1 * 8 + 7];
        float* dst = pb + (y * 8 + r1) * WP + xx * 8;
        *(float4*)dst = a0;
        *(float4*)(dst + 4) = a1;
    }
}

// =====================================================================
// K3: 9x9 local-max keep + candidate compaction (LDS compaction, 1 atomic/block)
// =====================================================================
__global__ __launch_bounds__(256) void nms_kernel(const float* __restrict__ prob,
                                                  float* __restrict__ keep_out,
                                                  float* __restrict__ cand,
                                                  int* __restrict__ cnt)
{
    __shared__ float xs[40][40];
    __shared__ float rmax[40][32];
    __shared__ float clist[1024];
    __shared__ int csh;
    __shared__ int gbase;

    int bid = blockIdx.x;
    int tx = bid % 20;
    int ty = (bid / 20) % 15;
    int b = bid / 300;
    const float* pb = prob + (size_t)b * (HP * WP);
    int t = threadIdx.x;

    if (t == 0) csh = 0;

    for (int idx = t; idx < 1600; idx += 256) {
        int c = idx % 40, r = idx / 40;
        int gy = ty * 32 - 4 + r;
        int gx = tx * 32 - 4 + c;
        float v = -INFINITY;
        if (gy >= 0 && gy < HP && gx >= 0 && gx < WP) v = pb[gy * WP + gx];
        xs[r][c] = v;
    }
    __syncthreads();

    for (int idx = t; idx < 1280; idx += 256) {
        int c = idx & 31, r = idx >> 5;
        float m = xs[r][c];
#pragma unroll
        for (int d = 1; d < 9; ++d) m = fmaxf(m, xs[r][c + d]);
        rmax[r][c] = m;
    }
    __syncthreads();

    for (int idx = t; idx < 1024; idx += 256) {
        int c = idx & 31, ro = idx >> 5;
        float m = rmax[ro][c];
#pragma unroll
        for (int d = 1; d < 9; ++d) m = fmaxf(m, rmax[ro + d][c]);
        float v = xs[ro + 4][c + 4];
        float keep = (v == m) ? v : 0.f;
        keep_out[(size_t)b * (HP * WP) + (ty * 32 + ro) * WP + tx * 32 + c] = keep;
        if (keep > 0.f) {
            int i = atomicAdd(&csh, 1);
            clist[i] = keep;
        }
    }
    __syncthreads();

    int m = csh;
    if (m > 0) {
        if (t == 0) gbase = atomicAdd(&cnt[b * 32], m);
        __syncthreads();
        int gb = gbase;
        for (int i = t; i < m; i += 256) {
            int dst = gb + i;
            if (dst < CAND_MAX) cand[b * CAND_MAX + dst] = clist[i];
        }
    }
}

// =====================================================================
// K4: exact kth-largest (k=1000) per batch via 4-pass radix select
// =====================================================================
__global__ __launch_bounds__(256) void select_kernel(const float* __restrict__ cand,
                                                     const int* __restrict__ cnt,
                                                     float* __restrict__ kth)
{
    __shared__ unsigned hist[256];
    __shared__ unsigned sh_prefix, sh_K;

    int b = blockIdx.x;
    int t = threadIdx.x;
    int n = cnt[b * 32];
    if (n > CAND_MAX) n = CAND_MAX;
    if (n < TOPK) {
        if (t == 0) kth[b] = 0.f;
        return;
    }
    if (t == 0) { sh_prefix = 0u; sh_K = TOPK; }
    __syncthreads();
    const float* cb = cand + b * CAND_MAX;

    for (int pass = 3; pass >= 0; --pass) {
        hist[t] = 0u;
        __syncthreads();
        unsigned prefix = sh_prefix;
        unsigned himask = (pass == 3) ? 0u : (0xFFFFFFFFu << ((pass + 1) * 8));
        for (int i = t; i < n; i += 256) {
            unsigned u = __float_as_uint(cb[i]);
            if ((u & himask) == prefix)
                atomicAdd(&hist[(u >> (pass * 8)) & 255], 1u);
        }
        __syncthreads();
        if (t == 0) {
            unsigned K = sh_K, cum = 0;
            int sel = 0;
            for (int v2 = 255; v2 >= 0; --v2) {
                if (cum + hist[v2] >= K) { sel = v2; sh_K = K - cum; break; }
                cum += hist[v2];
            }
            sh_prefix = prefix | ((unsigned)sel << (pass * 8));
        }
        __syncthreads();
    }
    if (t == 0) kth[b] = __uint_as_float(sh_prefix);
}

// =====================================================================
// K5: threshold with kth + binarize
// =====================================================================
__global__ __launch_bounds__(256) void thresh_kernel(const float* __restrict__ keep,
                                                     const float* __restrict__ kth,
                                                     float* __restrict__ prob_nms,
                                                     float* __restrict__ pred)
{
    int i4 = blockIdx.x * 256 + threadIdx.x;
    int b = i4 / (HP * WP / 4);
    float tv = kth[b];
    float4 v = ((const float4*)keep)[i4];
    float4 o;
    o.x = (v.x >= tv) ? v.x : 0.f;
    o.y = (v.y >= tv) ? v.y : 0.f;
    o.z = (v.z >= tv) ? v.z : 0.f;
    o.w = (v.w >= tv) ? v.w : 0.f;
    ((float4*)prob_nms)[i4] = o;
    float4 pr;
    pr.x = (o.x >= DET_THRESH) ? 1.f : 0.f;
    pr.y = (o.y >= DET_THRESH) ? 1.f : 0.f;
    pr.z = (o.z >= DET_THRESH) ? 1.f : 0.f;
    pr.w = (o.w >= DET_THRESH) ? 1.f : 0.f;
    ((float4*)pred)[i4] = pr;
}

// =====================================================================
extern "C" void kernel_launch(void* const* d_in, const int* in_sizes, int n_in,
                              void* d_out, int out_size, void* d_ws, size_t ws_size,
                              hipStream_t stream) {
    const float* x   = (const float*)d_in[0];
    const float* wa  = (const float*)d_in[1];
    const float* ba  = (const float*)d_in[2];
    const float* ga  = (const float*)d_in[3];
    const float* bta = (const float*)d_in[4];
    const float* ma  = (const float*)d_in[5];
    const float* va  = (const float*)d_in[6];
    const float* wb  = (const float*)d_in[7];
    const float* bb  = (const float*)d_in[8];
    const float* gb  = (const float*)d_in[9];
    const float* btb = (const float*)d_in[10];
    const float* mb  = (const float*)d_in[11];
    const float* vb  = (const float*)d_in[12];

    float* out = (float*)d_out;
    float* ws  = (float*)d_ws;

    float* wt3  = ws + WT_OFF;
    float* sa   = ws + SA_OFF;
    float* ta   = ws + TA_OFF;
    float* tbv  = ws + TB_OFF;
    float* wt1  = ws + WT1_OFF;
    float* h    = ws + H_OFF;
    float* cand = ws + CAND_OFF;
    int*   cnt  = (int*)(ws + CNT_OFF);
    float* kth  = ws + KTH_OFF;

    hipMemsetAsync((void*)cnt, 0, CNT_N * sizeof(int), stream);

    {
        int total = WT_N + 256 + COUT + WT1_N;
        prep_kernel<<<(total + 255) / 256, 256, 0, stream>>>(
            wa, ba, ga, bta, ma, va, wb, bb, gb, btb, mb, vb, wt3, sa, ta, tbv, wt1);
    }

    conv3_kernel<<<B_ * 80, 256, 0, stream>>>(x, wt3, sa, ta, h);

    conv1_kernel<<<(B_ * H_ * W_) / 256, 256, 0, stream>>>(
        h, wt1, tbv, out, out + PROB_OFF);

    nms_kernel<<<32 * 15 * 20, 256, 0, stream>>>(
        out + PROB_OFF, out + NMS_OFF, cand, cnt);

    select_kernel<<<B_, 256, 0, stream>>>(cand, cnt, kth);

    thresh_kernel<<<(PROB_N / 4) / 256, 256, 0, stream>>>(
        out + NMS_OFF, kth, out + NMS_OFF, out + PRED_OFF);
}

// Round 6
// 764.533 us; speedup vs baseline: 12.3279x; 2.3322x over previous
//
#include <hip/hip_runtime.h>
#include <math.h>

typedef short s16x8 __attribute__((ext_vector_type(8)));
typedef float f32x4 __attribute__((ext_vector_type(4)));
typedef unsigned short u16;

// ---------------- problem constants ----------------
#define B_    32
#define CIN   128
#define CHID  256
#define H_    60
#define W_    80
#define COUT  65
#define HP    480
#define WP    640
#define TOPK  1000
#define CAND_MAX 8192
#define DET_THRESH 0.015f

// ---------------- output layout (floats) ----------------
#define LOGITS_N (B_*COUT*H_*W_)
#define PROB_N   (B_*HP*WP)
#define PROB_OFF (LOGITS_N)
#define NMS_OFF  (PROB_OFF + PROB_N)
#define PRED_OFF (NMS_OFF + PROB_N)

// ---------------- workspace layout (float offsets) ----------------
// WB: conv3 weights as 3 bf16 planes, [ocq4][icc4][tap9][split3][ocl64][icl32 swz]
#define WB_U16N  884736
#define WB_FN    442368
#define SA_OFF   WB_FN
#define TA_OFF   (SA_OFF + 256)
#define TB_OFF   (TA_OFF + 256)
#define WT1_N    (COUT*CHID)
#define WT1_OFF  (TB_OFF + 128)
#define H_OFF    (WT1_OFF + WT1_N)
#define H_N      (B_*H_*W_*CHID)
#define CAND_OFF (H_OFF + H_N)
#define CNT_OFF  (CAND_OFF + B_*CAND_MAX)
#define CNT_N    (32*32)
#define KTH_OFF  (CNT_OFF + CNT_N)
#define WT_N     (CHID*CIN*9)

// bf16 helpers (RNE)
__device__ __forceinline__ u16 f2bf(float x) {
    unsigned u = __float_as_uint(x);
    return (u16)((u + 0x7fffu + ((u >> 16) & 1u)) >> 16);
}
__device__ __forceinline__ float bf2f(u16 h) {
    return __uint_as_float(((unsigned)h) << 16);
}

// async global->LDS, 16B per lane (lds dest = uniform base + lane*16)
__device__ __forceinline__ void gload_lds16(const float* g, float* l) {
    __builtin_amdgcn_global_load_lds(
        (const __attribute__((address_space(1))) void*)g,
        (__attribute__((address_space(3))) void*)l, 16, 0, 0);
}

#define MFMA16 __builtin_amdgcn_mfma_f32_16x16x32_bf16

// =====================================================================
// K0: prep — WB (conv3 weights 3-way exact bf16 split, swizzled),
// sa/ta conv3 BN, tb + wt1 (conv1 folded).
// =====================================================================
__global__ void prep_kernel(const float* __restrict__ wa,
                            const float* __restrict__ ba, const float* __restrict__ ga,
                            const float* __restrict__ bta, const float* __restrict__ ma,
                            const float* __restrict__ va,
                            const float* __restrict__ wb, const float* __restrict__ bb,
                            const float* __restrict__ gb, const float* __restrict__ btb,
                            const float* __restrict__ mb, const float* __restrict__ vb,
                            u16* __restrict__ WBo,
                            float* __restrict__ sa, float* __restrict__ ta,
                            float* __restrict__ tb, float* __restrict__ wt1)
{
    int gid = blockIdx.x * 256 + threadIdx.x;
    if (gid < WT_N) {
        int icl = gid & 31;
        int ocl = (gid >> 5) & 63;
        int rest = gid >> 11;          // [0,144)
        int tap = rest % 9;
        int cq = rest / 9;             // [0,16)
        int icc = cq & 3, ocq = cq >> 2;
        float v = wa[(((ocq * 64 + ocl) * CIN) + icc * 32 + icl) * 9 + tap];
        u16 hh = f2bf(v); float r1 = v - bf2f(hh);
        u16 mm2 = f2bf(r1); float r2 = r1 - bf2f(mm2);
        u16 ll = f2bf(r2);
        size_t base = ((size_t)((ocq * 4 + icc) * 9 + tap) * 3) * 2048
                      + ocl * 32 + (icl ^ ((ocl & 3) << 3));
        WBo[base] = hh;
        WBo[base + 2048] = mm2;
        WBo[base + 4096] = ll;
    } else if (gid < WT_N + 256) {
        int oc = gid - WT_N;
        float inv = ga[oc] / sqrtf(va[oc] + 1e-5f);
        sa[oc] = inv;
        ta[oc] = (ba[oc] - ma[oc]) * inv + bta[oc];
    } else if (gid < WT_N + 256 + COUT) {
        int oc = gid - (WT_N + 256);
        float inv = gb[oc] / sqrtf(vb[oc] + 1e-5f);
        tb[oc] = (bb[oc] - mb[oc]) * inv + btb[oc];
    } else if (gid < WT_N + 256 + COUT + WT1_N) {
        int i = gid - (WT_N + 256 + COUT);
        int oc = i >> 8;
        float inv = gb[oc] / sqrtf(vb[oc] + 1e-5f);
        wt1[i] = wb[i] * inv;
    }
}

// =====================================================================
// K1: conv3x3 via split-bf16 MFMA (6-term, f32-equivalent numerics).
// Block: 64 px (4y x 16x) x 256 oc. Wave w = 64px x 64oc (ocq = w).
// K-step = 32 ic of one tap. A staged per icc (shared), B per (icc,tap).
// =====================================================================
__global__ __launch_bounds__(256) void conv3_kernel(const float* __restrict__ x,
                                                    const u16* __restrict__ WB,
                                                    const float* __restrict__ sa,
                                                    const float* __restrict__ ta,
                                                    float* __restrict__ h)
{
    __shared__ __align__(16) u16 xsA[3 * 3456];      // 20736 B: x hi/mid/lo planes
    __shared__ __align__(16) u16 wsB[4 * 3 * 2048];  // 49152 B: per-wave oc slice

    // bijective XCD swizzle: 2400 blocks = 8 * 300
    int d = blockIdx.x;
    int o = (d & 7) * 300 + (d >> 3);
    int tile = o % 75;
    int b = o / 75;
    int ty = tile / 5, tx = tile % 5;
    int y0 = ty * 4, x0 = tx * 16;

    int t = threadIdx.x;
    int wv = __builtin_amdgcn_readfirstlane(t >> 6);   // 0..3 = ocq
    int lane = t & 63;
    int cx = lane & 15;
    int kg = lane >> 4;            // 0..3
    int icl0 = kg * 8;

    const float* xb = x + (size_t)b * CIN * H_ * W_;

    f32x4 acc[4][4];               // [pb(y-row)][f(oc-subtile)]
#pragma unroll
    for (int pb = 0; pb < 4; ++pb)
#pragma unroll
        for (int f = 0; f < 4; ++f) acc[pb][f] = (f32x4)(0.f);

#pragma unroll 1
    for (int icc = 0; icc < 4; ++icc) {
#pragma unroll 1
        for (int tap = 0; tap < 9; ++tap) {
            __syncthreads();   // previous phase's reads done; buffers reusable

            // stage this wave's B slice (12 KB) via global_load_lds
            {
                const u16* src = WB + (size_t)(((wv * 4 + icc) * 9 + tap) * 3) * 2048;
                u16* dst = wsB + wv * 6144;
#pragma unroll
                for (int idx = 0; idx < 12; ++idx)
                    gload_lds16((const float*)(src + idx * 512 + lane * 8),
                                (float*)(dst + idx * 512));
            }
            // stage A slab (once per icc): f32 -> exact 3-way bf16 split
            if (tap == 0) {
                const float* xc = xb + icc * 32 * (H_ * W_);
#pragma unroll
                for (int j = 0; j < 14; ++j) {
                    int e = t + j * 256;
                    if (e < 3456) {
                        int icl = e / 108;
                        int rem = e - icl * 108;
                        int yy = rem / 18;
                        int xx = rem - yy * 18;
                        int gy = y0 + yy - 1, gx = x0 + xx - 1;
                        float v = 0.f;
                        if (gy >= 0 && gy < H_ && gx >= 0 && gx < W_)
                            v = xc[icl * (H_ * W_) + gy * W_ + gx];
                        u16 hh = f2bf(v); float r1 = v - bf2f(hh);
                        u16 mm2 = f2bf(r1); float r2 = r1 - bf2f(mm2);
                        u16 ll = f2bf(r2);
                        int wu = (yy * 18 + xx) * 32 + (icl ^ ((xx & 3) << 3));
                        xsA[wu] = hh;
                        xsA[3456 + wu] = mm2;
                        xsA[6912 + wu] = ll;
                    }
                }
            }
            __syncthreads();   // drains gload vmcnt + lds writes

            int dy = tap / 3, dx = tap - dy * 3;

            // load all B frags for this wave (held across pb loop)
            s16x8 Bh[4], Bm[4], Bl[4];
            const u16* wbB = wsB + wv * 6144;
#pragma unroll
            for (int f = 0; f < 4; ++f) {
                int oc = f * 16 + cx;
                int bu = oc * 32 + (icl0 ^ ((oc & 3) << 3));
                Bh[f] = *(const s16x8*)&wbB[bu];
                Bm[f] = *(const s16x8*)&wbB[2048 + bu];
                Bl[f] = *(const s16x8*)&wbB[4096 + bu];
            }

            int cxd = cx + dx;
            int sw = (cxd & 3) << 3;
#pragma unroll
            for (int pb = 0; pb < 4; ++pb) {
                int au = ((pb + dy) * 18 + cxd) * 32 + (icl0 ^ sw);
                s16x8 Ah = *(const s16x8*)&xsA[au];
                s16x8 Am = *(const s16x8*)&xsA[3456 + au];
                s16x8 Al = *(const s16x8*)&xsA[6912 + au];
#pragma unroll
                for (int f = 0; f < 4; ++f) {
                    acc[pb][f] = MFMA16(Ah, Bh[f], acc[pb][f], 0, 0, 0);
                    acc[pb][f] = MFMA16(Ah, Bm[f], acc[pb][f], 0, 0, 0);
                    acc[pb][f] = MFMA16(Am, Bh[f], acc[pb][f], 0, 0, 0);
                    acc[pb][f] = MFMA16(Ah, Bl[f], acc[pb][f], 0, 0, 0);
                    acc[pb][f] = MFMA16(Am, Bm[f], acc[pb][f], 0, 0, 0);
                    acc[pb][f] = MFMA16(Al, Bh[f], acc[pb][f], 0, 0, 0);
                }
            }
        }
    }

    // epilogue: C lane map n=lane&15, m=(lane>>4)*4+r; BN + ReLU
#pragma unroll
    for (int f = 0; f < 4; ++f) {
        int oc = wv * 64 + f * 16 + cx;
        float s_ = sa[oc], t_ = ta[oc];
#pragma unroll
        for (int pb = 0; pb < 4; ++pb) {
            int y = y0 + pb;
#pragma unroll
            for (int r = 0; r < 4; ++r) {
                int cxr = kg * 4 + r;
                size_t addr = ((size_t)(b * (H_ * W_) + y * W_ + x0 + cxr)) * CHID + oc;
                h[addr] = fmaxf(fmaf(acc[pb][f][r], s_, t_), 0.f);
            }
        }
    }
}

// =====================================================================
// K2: conv1x1 (256->65) + BN: weights staged in 64KB LDS via gload_lds
// =====================================================================
__global__ __launch_bounds__(256) void conv1_kernel(const float* __restrict__ h,
                                                    const float* __restrict__ wt1,
                                                    const float* __restrict__ tb,
                                                    float* __restrict__ logits,
                                                    float* __restrict__ prob)
{
    __shared__ __align__(16) float ws_[64 * 256];
    int t = threadIdx.x;
    int wave = t >> 6, lane = t & 63;

    for (int k = wave; k < 64; k += 4)
        gload_lds16(wt1 + k * 256 + lane * 4, &ws_[k * 256]);

    int p = blockIdx.x * 256 + t;
    const float* hp = h + (size_t)p * CHID;
    const float* w64g = wt1 + 64 * 256;

    float acc[COUT];
#pragma unroll
    for (int oc = 0; oc < COUT; ++oc) acc[oc] = 0.f;

    __syncthreads();

#pragma unroll 2
    for (int kc = 0; kc < 32; ++kc) {
        float4 h0 = *(const float4*)(hp + kc * 8);
        float4 h1 = *(const float4*)(hp + kc * 8 + 4);
        float hv[8] = {h0.x, h0.y, h0.z, h0.w, h1.x, h1.y, h1.z, h1.w};
        {
            float4 w0 = *(const float4*)(w64g + kc * 8);
            float4 w1 = *(const float4*)(w64g + kc * 8 + 4);
            float a = acc[64];
            a = fmaf(w0.x, hv[0], a); a = fmaf(w0.y, hv[1], a);
            a = fmaf(w0.z, hv[2], a); a = fmaf(w0.w, hv[3], a);
            a = fmaf(w1.x, hv[4], a); a = fmaf(w1.y, hv[5], a);
            a = fmaf(w1.z, hv[6], a); a = fmaf(w1.w, hv[7], a);
            acc[64] = a;
        }
#pragma unroll
        for (int oc = 0; oc < 64; ++oc) {
            const float* wr = ws_ + oc * 256 + kc * 8;
            float4 w0 = *(const float4*)wr;
            float4 w1 = *(const float4*)(wr + 4);
            float a = acc[oc];
            a = fmaf(w0.x, hv[0], a); a = fmaf(w0.y, hv[1], a);
            a = fmaf(w0.z, hv[2], a); a = fmaf(w0.w, hv[3], a);
            a = fmaf(w1.x, hv[4], a); a = fmaf(w1.y, hv[5], a);
            a = fmaf(w1.z, hv[6], a); a = fmaf(w1.w, hv[7], a);
            acc[oc] = a;
        }
    }

    int b = p / (H_ * W_);
    int yx = p % (H_ * W_);
    int y = yx / W_;
    int xx = yx % W_;

    float v[COUT];
#pragma unroll
    for (int oc = 0; oc < COUT; ++oc)
        v[oc] = acc[oc] + tb[oc];

#pragma unroll
    for (int oc = 0; oc < COUT; ++oc)
        logits[((size_t)(b * COUT + oc)) * (H_ * W_) + yx] = v[oc];

    float* pb = prob + (size_t)b * (HP * WP);
#pragma unroll
    for (int r1 = 0; r1 < 8; ++r1) {
        float4 a0, a1;
        a0.x = v[r1 * 8 + 0]; a0.y = v[r1 * 8 + 1]; a0.z = v[r1 * 8 + 2]; a0.w = v[r1 * 8 + 3];
        a1.x = v[r1 * 8 + 4]; a1.y = v[r1 * 8 + 5]; a1.z = v[r1 * 8 + 6]; a1.w = v[r1 * 8 + 7];
        float* dst = pb + (y * 8 + r1) * WP + xx * 8;
        *(float4*)dst = a0;
        *(float4*)(dst + 4) = a1;
    }
}

// =====================================================================
// K3: 9x9 local-max keep + candidate compaction (1 global atomic/block)
// =====================================================================
__global__ __launch_bounds__(256) void nms_kernel(const float* __restrict__ prob,
                                                  float* __restrict__ keep_out,
                                                  float* __restrict__ cand,
                                                  int* __restrict__ cnt)
{
    __shared__ float xs[40][40];
    __shared__ float rmax[40][32];
    __shared__ float clist[1024];
    __shared__ int csh;
    __shared__ int gbase;

    int bid = blockIdx.x;
    int tx = bid % 20;
    int ty = (bid / 20) % 15;
    int b = bid / 300;
    const float* pb = prob + (size_t)b * (HP * WP);
    int t = threadIdx.x;

    if (t == 0) csh = 0;

    for (int idx = t; idx < 1600; idx += 256) {
        int c = idx % 40, r = idx / 40;
        int gy = ty * 32 - 4 + r;
        int gx = tx * 32 - 4 + c;
        float v = -INFINITY;
        if (gy >= 0 && gy < HP && gx >= 0 && gx < WP) v = pb[gy * WP + gx];
        xs[r][c] = v;
    }
    __syncthreads();

    for (int idx = t; idx < 1280; idx += 256) {
        int c = idx & 31, r = idx >> 5;
        float m = xs[r][c];
#pragma unroll
        for (int d = 1; d < 9; ++d) m = fmaxf(m, xs[r][c + d]);
        rmax[r][c] = m;
    }
    __syncthreads();

    for (int idx = t; idx < 1024; idx += 256) {
        int c = idx & 31, ro = idx >> 5;
        float m = rmax[ro][c];
#pragma unroll
        for (int d = 1; d < 9; ++d) m = fmaxf(m, rmax[ro + d][c]);
        float v = xs[ro + 4][c + 4];
        float keep = (v == m) ? v : 0.f;
        keep_out[(size_t)b * (HP * WP) + (ty * 32 + ro) * WP + tx * 32 + c] = keep;
        if (keep > 0.f) {
            int i = atomicAdd(&csh, 1);
            clist[i] = keep;
        }
    }
    __syncthreads();

    int m = csh;
    if (m > 0) {
        if (t == 0) gbase = atomicAdd(&cnt[b * 32], m);
        __syncthreads();
        int gb = gbase;
        for (int i = t; i < m; i += 256) {
            int dst = gb + i;
            if (dst < CAND_MAX) cand[b * CAND_MAX + dst] = clist[i];
        }
    }
}

// =====================================================================
// K4: exact kth-largest (k=1000) per batch via 4-pass radix select
// =====================================================================
__global__ __launch_bounds__(256) void select_kernel(const float* __restrict__ cand,
                                                     const int* __restrict__ cnt,
                                                     float* __restrict__ kth)
{
    __shared__ unsigned hist[256];
    __shared__ unsigned sh_prefix, sh_K;

    int b = blockIdx.x;
    int t = threadIdx.x;
    int n = cnt[b * 32];
    if (n > CAND_MAX) n = CAND_MAX;
    if (n < TOPK) {
        if (t == 0) kth[b] = 0.f;
        return;
    }
    if (t == 0) { sh_prefix = 0u; sh_K = TOPK; }
    __syncthreads();
    const float* cb = cand + b * CAND_MAX;

    for (int pass = 3; pass >= 0; --pass) {
        hist[t] = 0u;
        __syncthreads();
        unsigned prefix = sh_prefix;
        unsigned himask = (pass == 3) ? 0u : (0xFFFFFFFFu << ((pass + 1) * 8));
        for (int i = t; i < n; i += 256) {
            unsigned u = __float_as_uint(cb[i]);
            if ((u & himask) == prefix)
                atomicAdd(&hist[(u >> (pass * 8)) & 255], 1u);
        }
        __syncthreads();
        if (t == 0) {
            unsigned K = sh_K, cum = 0;
            int sel = 0;
            for (int v2 = 255; v2 >= 0; --v2) {
                if (cum + hist[v2] >= K) { sel = v2; sh_K = K - cum; break; }
                cum += hist[v2];
            }
            sh_prefix = prefix | ((unsigned)sel << (pass * 8));
        }
        __syncthreads();
    }
    if (t == 0) kth[b] = __uint_as_float(sh_prefix);
}

// =====================================================================
// K5: threshold with kth + binarize
// =====================================================================
__global__ __launch_bounds__(256) void thresh_kernel(const float* __restrict__ keep,
                                                     const float* __restrict__ kth,
                                                     float* __restrict__ prob_nms,
                                                     float* __restrict__ pred)
{
    int i4 = blockIdx.x * 256 + threadIdx.x;
    int b = i4 / (HP * WP / 4);
    float tv = kth[b];
    float4 v = ((const float4*)keep)[i4];
    float4 o;
    o.x = (v.x >= tv) ? v.x : 0.f;
    o.y = (v.y >= tv) ? v.y : 0.f;
    o.z = (v.z >= tv) ? v.z : 0.f;
    o.w = (v.w >= tv) ? v.w : 0.f;
    ((float4*)prob_nms)[i4] = o;
    float4 pr;
    pr.x = (o.x >= DET_THRESH) ? 1.f : 0.f;
    pr.y = (o.y >= DET_THRESH) ? 1.f : 0.f;
    pr.z = (o.z >= DET_THRESH) ? 1.f : 0.f;
    pr.w = (o.w >= DET_THRESH) ? 1.f : 0.f;
    ((float4*)pred)[i4] = pr;
}

// =====================================================================
extern "C" void kernel_launch(void* const* d_in, const int* in_sizes, int n_in,
                              void* d_out, int out_size, void* d_ws, size_t ws_size,
                              hipStream_t stream) {
    const float* x   = (const float*)d_in[0];
    const float* wa  = (const float*)d_in[1];
    const float* ba  = (const float*)d_in[2];
    const float* ga  = (const float*)d_in[3];
    const float* bta = (const float*)d_in[4];
    const float* ma  = (const float*)d_in[5];
    const float* va  = (const float*)d_in[6];
    const float* wb  = (const float*)d_in[7];
    const float* bb  = (const float*)d_in[8];
    const float* gb  = (const float*)d_in[9];
    const float* btb = (const float*)d_in[10];
    const float* mb  = (const float*)d_in[11];
    const float* vb  = (const float*)d_in[12];

    float* out = (float*)d_out;
    float* ws  = (float*)d_ws;

    u16*   WB   = (u16*)ws;
    float* sa   = ws + SA_OFF;
    float* ta   = ws + TA_OFF;
    float* tbv  = ws + TB_OFF;
    float* wt1  = ws + WT1_OFF;
    float* h    = ws + H_OFF;
    float* cand = ws + CAND_OFF;
    int*   cnt  = (int*)(ws + CNT_OFF);
    float* kth  = ws + KTH_OFF;

    hipMemsetAsync((void*)cnt, 0, CNT_N * sizeof(int), stream);

    {
        int total = WT_N + 256 + COUT + WT1_N;
        prep_kernel<<<(total + 255) / 256, 256, 0, stream>>>(
            wa, ba, ga, bta, ma, va, wb, bb, gb, btb, mb, vb, WB, sa, ta, tbv, wt1);
    }

    conv3_kernel<<<2400, 256, 0, stream>>>(x, WB, sa, ta, h);

    conv1_kernel<<<(B_ * H_ * W_) / 256, 256, 0, stream>>>(
        h, wt1, tbv, out, out + PROB_OFF);

    nms_kernel<<<32 * 15 * 20, 256, 0, stream>>>(
        out + PROB_OFF, out + NMS_OFF, cand, cnt);

    select_kernel<<<B_, 256, 0, stream>>>(cand, cnt, kth);

    thresh_kernel<<<(PROB_N / 4) / 256, 256, 0, stream>>>(
        out + NMS_OFF, kth, out + NMS_OFF, out + PRED_OFF);
}